// Round 9
// baseline (384.888 us; speedup 1.0000x reference)
//
#include <hip/hip_runtime.h>
#include <hip/hip_bf16.h>

#define NEG_SLOPE 0.2f

typedef unsigned short u16;
typedef u16 u16x8 __attribute__((ext_vector_type(8)));
typedef u16 u16x4 __attribute__((ext_vector_type(4)));
typedef short s16x8 __attribute__((ext_vector_type(8)));
typedef float f32x4 __attribute__((ext_vector_type(4)));

__device__ __forceinline__ u16 f2bf(float x) {
    unsigned u = __float_as_uint(x);
    return (u16)((u + 0x7fffu + ((u >> 16) & 1u)) >> 16);
}
__device__ __forceinline__ float bf2f(u16 h) {
    return __uint_as_float(((unsigned)h) << 16);
}

// ---------------------------------------------------------------------------
// split fp32 -> bf16 hi + lo(residual), both sides in one dispatch (grid.y)
// ---------------------------------------------------------------------------
__global__ __launch_bounds__(256) void splitx_k(
    const float* __restrict__ x0, const float* __restrict__ x1,
    u16* __restrict__ Xh, u16* __restrict__ Xl, int per_side4)
{
    int i = blockIdx.x * 256 + threadIdx.x;
    if (i >= per_side4) return;
    int side = blockIdx.y;
    const float* X = side ? x1 : x0;
    size_t o = (size_t)side * per_side4 * 4 + (size_t)i * 4;
    float4 v = *(const float4*)(X + (size_t)i * 4);
    float f[4] = { v.x, v.y, v.z, v.w };
    u16x4 hi, lo;
    #pragma unroll
    for (int j = 0; j < 4; ++j) {
        u16 h = f2bf(f[j]);
        hi[j] = h;
        lo[j] = f2bf(f[j] - bf2f(h));
    }
    *(u16x4*)(Xh + o) = hi;
    *(u16x4*)(Xl + o) = lo;
}

// ---------------------------------------------------------------------------
// all 4 weight tensors: W[h][k][f] -> Wct[which][col=h*64+f][k] hi/lo
// which = side*2+layer: {u0,u1,t0,t1}
// ---------------------------------------------------------------------------
__global__ __launch_bounds__(256) void wsplit4_k(
    const float* __restrict__ w0, const float* __restrict__ w1,
    const float* __restrict__ w2, const float* __restrict__ w3,
    u16* __restrict__ Wht, u16* __restrict__ Wlt)
{
    int tid = blockIdx.x * 256 + threadIdx.x;     // 0..262143
    int which = tid >> 16;
    int idx = tid & 65535;
    const float* W = (which == 0) ? w0 : (which == 1) ? w1 : (which == 2) ? w2 : w3;
    int f = idx & 63, k = (idx >> 6) & 255, h = idx >> 14;
    float x = W[idx];
    u16 hi = f2bf(x);
    u16 lo = f2bf(x - bf2f(hi));
    int o = (which << 16) + (h * 64 + f) * 256 + k;
    Wht[o] = hi; Wlt[o] = lo;
}

// ---------------------------------------------------------------------------
// MFMA GEMM v5 (bf16x3): block = 64 rows x 256 cols (ALL heads), wave = head.
// Both sides in one dispatch (blockIdx.y). K-step 32, LDS stride 40 u16.
// Fused attn projections: shfl-16 reduce, plain store (unique writer).
// ---------------------------------------------------------------------------
__global__ __launch_bounds__(256) void gemm_mfma_k(
    const u16* __restrict__ xh_all, const u16* __restrict__ xl_all,  // [2][n*256]
    const u16* __restrict__ Wht, const u16* __restrict__ Wlt,        // [4][65536]
    const float* __restrict__ au_s, const float* __restrict__ au_t,
    const float* __restrict__ at_s, const float* __restrict__ at_t,
    u16* __restrict__ hpb_all,                                       // [2][n*256]
    float* __restrict__ asat,                                        // [4][n*8]
    int layer, int n)
{
    const int side = blockIdx.y;
    const int row0 = blockIdx.x * 64;
    const int t = threadIdx.x;
    const int l = t & 63;
    const int h = t >> 6;                 // wave = head
    const int which = side * 2 + layer;

    const u16* Xh = xh_all + (size_t)side * n * 256;
    const u16* Xl = xl_all + (size_t)side * n * 256;
    const u16* Wh = Wht + ((size_t)which << 16);
    const u16* Wl = Wlt + ((size_t)which << 16);
    const float* a_src = (side ? at_s : au_s) + h * 64;
    const float* a_trg = (side ? at_t : au_t) + h * 64;
    u16* HPB = hpb_all + (size_t)side * n * 256;
    float* as_ = asat + (size_t)which * n * 8;
    float* at_ = as_ + (size_t)n * 4;

    __shared__ u16 Ah[64 * 40], Al[64 * 40], Bh[256 * 40], Bl[256 * 40];

    const int sr = t >> 2, sp = t & 3;
    const int arow = (row0 + sr < n) ? (row0 + sr) : (n - 1);
    const u16* gAh = Xh + (size_t)arow * 256 + sp * 8;
    const u16* gAl = Xl + (size_t)arow * 256 + sp * 8;
    const int lda = sr * 40 + sp * 8;

    const int fb = l & 15;
    const int kg = l >> 4;
    int ra[4], cb[4];
    #pragma unroll
    for (int r = 0; r < 4; ++r) ra[r] = (r * 16 + fb) * 40 + kg * 8;
    #pragma unroll
    for (int c = 0; c < 4; ++c) cb[c] = (h * 64 + c * 16 + fb) * 40 + kg * 8;

    f32x4 acc[4][4];
    #pragma unroll
    for (int r = 0; r < 4; ++r)
        #pragma unroll
        for (int c = 0; c < 4; ++c) acc[r][c] = f32x4{0.f, 0.f, 0.f, 0.f};

    for (int k0 = 0; k0 < 256; k0 += 32) {
        __syncthreads();
        *(u16x8*)&Ah[lda] = *(const u16x8*)(gAh + k0);
        *(u16x8*)&Al[lda] = *(const u16x8*)(gAl + k0);
        #pragma unroll
        for (int i = 0; i < 4; ++i) {
            int j = t + i * 256;
            int col = j >> 2, cp = j & 3;
            int ofs = col * 40 + cp * 8;
            *(u16x8*)&Bh[ofs] = *(const u16x8*)(Wh + (size_t)col * 256 + k0 + cp * 8);
            *(u16x8*)&Bl[ofs] = *(const u16x8*)(Wl + (size_t)col * 256 + k0 + cp * 8);
        }
        __syncthreads();

        s16x8 bh[4], bl[4];
        #pragma unroll
        for (int c = 0; c < 4; ++c) {
            bh[c] = *(const s16x8*)&Bh[cb[c]];
            bl[c] = *(const s16x8*)&Bl[cb[c]];
        }
        #pragma unroll
        for (int r = 0; r < 4; ++r) {
            s16x8 ah = *(const s16x8*)&Ah[ra[r]];
            s16x8 al = *(const s16x8*)&Al[ra[r]];
            #pragma unroll
            for (int c = 0; c < 4; ++c) {
                acc[r][c] = __builtin_amdgcn_mfma_f32_16x16x32_bf16(ah, bh[c], acc[r][c], 0, 0, 0);
                acc[r][c] = __builtin_amdgcn_mfma_f32_16x16x32_bf16(ah, bl[c], acc[r][c], 0, 0, 0);
                acc[r][c] = __builtin_amdgcn_mfma_f32_16x16x32_bf16(al, bh[c], acc[r][c], 0, 0, 0);
            }
        }
    }

    float pav[4], pbv[4];
    #pragma unroll
    for (int c = 0; c < 4; ++c) { pav[c] = a_src[c * 16 + fb]; pbv[c] = a_trg[c * 16 + fb]; }

    #pragma unroll
    for (int r = 0; r < 4; ++r) {
        #pragma unroll
        for (int q = 0; q < 4; ++q) {
            int grow = row0 + r * 16 + kg * 4 + q;
            float s = 0.f, u = 0.f;
            if (grow < n) {
                u16* hrow = HPB + (size_t)grow * 256 + h * 64 + fb;
                #pragma unroll
                for (int c = 0; c < 4; ++c) {
                    float v = acc[r][c][q];
                    s += v * pav[c];
                    u += v * pbv[c];
                    hrow[c * 16] = f2bf(v);
                }
            }
            #pragma unroll
            for (int off = 8; off; off >>= 1) {
                s += __shfl_xor(s, off, 16);
                u += __shfl_xor(u, off, 16);
            }
            if (grow < n && fb == 0) {
                as_[grow * 4 + h] = s;
                at_[grow * 4 + h] = u;
            }
        }
    }
}

// ---------------------------------------------------------------------------
// CSR build, both sides merged; scatter also records sorted trg.
// ---------------------------------------------------------------------------
__global__ void hist2_k(const int* __restrict__ tu, const int* __restrict__ tt,
                        int* __restrict__ counts, int* __restrict__ ranks,
                        int E, int N)
{
    int e = blockIdx.x * blockDim.x + threadIdx.x;
    if (e < E)          ranks[e] = atomicAdd(&counts[tu[e]], 1);
    else if (e < 2 * E) ranks[e] = atomicAdd(&counts[N + tt[e - E]], 1);
}

__global__ __launch_bounds__(1024) void scan2_k(const int* __restrict__ counts_all,
                                                int* __restrict__ starts_all, int n)
{
    const int T = 1024;
    const int* counts = counts_all + blockIdx.x * n;
    int* starts = starts_all + blockIdx.x * (n + 1);
    int t = threadIdx.x;
    int chunk = (n + T - 1) / T;
    int beg = t * chunk;
    int end = min(beg + chunk, n);
    int sum = 0;
    for (int i = beg; i < end; ++i) sum += counts[i];
    __shared__ int lds[T];
    lds[t] = sum;
    __syncthreads();
    for (int off = 1; off < T; off <<= 1) {
        int v = (t >= off) ? lds[t - off] : 0;
        __syncthreads();
        lds[t] += v;
        __syncthreads();
    }
    int run = lds[t] - sum;
    for (int i = beg; i < end; ++i) { starts[i] = run; run += counts[i]; }
    if (t == T - 1) starts[n] = lds[T - 1];
}

__global__ void scatter2_k(const int* __restrict__ su, const int* __restrict__ st,
                           const int* __restrict__ tu, const int* __restrict__ tt,
                           const int* __restrict__ starts_all,
                           const int* __restrict__ ranks,
                           int* __restrict__ srcs, int* __restrict__ trgs,
                           int E, int N)
{
    int e = blockIdx.x * blockDim.x + threadIdx.x;
    if (e < E) {
        int pos = starts_all[tu[e]] + ranks[e];
        srcs[pos] = su[e];
        trgs[pos] = tu[e];
    } else if (e < 2 * E) {
        int ee = e - E;
        const int* st1 = starts_all + (N + 1);
        int pos = E + st1[tt[ee]] + ranks[e];
        srcs[pos] = st[ee];
        trgs[pos] = tt[ee];
    }
}

// ---------------------------------------------------------------------------
// Edge-parallel attention-weight precompute (sorted edge order):
// p4[side][j][h] = __expf(leaky(as[src_j][h] + at[trg_j][h]))
// ---------------------------------------------------------------------------
__global__ __launch_bounds__(256) void pexp_k(
    const int* __restrict__ srcs2, const int* __restrict__ trgs2,
    const float* __restrict__ asat, float* __restrict__ p4,
    int layer, int n, int E)
{
    int j = blockIdx.x * 256 + threadIdx.x;
    if (j >= E) return;
    int side = blockIdx.y;
    const float* as_ = asat + (size_t)(side * 2 + layer) * n * 8;
    const float* at_ = as_ + (size_t)n * 4;
    int s = srcs2[(size_t)side * E + j];
    int v = trgs2[(size_t)side * E + j];
    float4 a = *(const float4*)(as_ + s * 4);
    float4 b = *(const float4*)(at_ + v * 4);
    float4 p;
    float x;
    x = a.x + b.x; p.x = __expf(fmaxf(x, NEG_SLOPE * x));
    x = a.y + b.y; p.y = __expf(fmaxf(x, NEG_SLOPE * x));
    x = a.z + b.z; p.z = __expf(fmaxf(x, NEG_SLOPE * x));
    x = a.w + b.w; p.w = __expf(fmaxf(x, NEG_SLOPE * x));
    *(float4*)(p4 + ((size_t)side * E + j) * 4) = p;
}

// ---------------------------------------------------------------------------
// Aggregation: one WAVE per node, both sides (blockIdx.y), bf16 gather.
// Inner loop: wave-uniform loads of src & p (broadcast), hp row gather,
// 4 cvt + 4 fma per lane. No shuffle, no exp, 32-bit index math.
// LAYER 0: elu+split -> xh/xl. LAYER 1: head-mean -> of.
// ---------------------------------------------------------------------------
template<int LAYER>
__global__ __launch_bounds__(256) void aggregate_k(
    const u16* __restrict__ hpb_all, const float* __restrict__ p4,
    const int* __restrict__ starts2, const int* __restrict__ srcs2,
    u16* __restrict__ oh_all, u16* __restrict__ ol_all,
    float* __restrict__ of_all, int n, int E)
{
    const int side = blockIdx.y;
    const int w = threadIdx.x >> 6;
    const int l = threadIdx.x & 63;
    const int v = blockIdx.x * 4 + w;
    if (v >= n) return;
    const int h = l >> 4;

    const u16* hp_l = hpb_all + (size_t)side * n * 256 + l * 4;  // + s*256 per edge
    const int* starts = starts2 + side * (n + 1);
    const int* srcs = srcs2 + (size_t)side * E;
    const float* pp = p4 + (size_t)side * E * 4 + h;             // + j*4 per edge

    const int s0 = starts[v], s1 = starts[v + 1];

    float4 ac0 = make_float4(0.f, 0.f, 0.f, 0.f), ac1 = ac0, ac2 = ac0, ac3 = ac0;
    float dn0 = 0.f, dn1 = 0.f, dn2 = 0.f, dn3 = 0.f;

    int j = s0;
    for (; j + 3 < s1; j += 4) {
        int sa = srcs[j], sb = srcs[j + 1], sc = srcs[j + 2], sd = srcs[j + 3];
        float pA = pp[(j + 0) * 4], pB = pp[(j + 1) * 4];
        float pC = pp[(j + 2) * 4], pD = pp[(j + 3) * 4];
        u16x4 va = *(const u16x4*)(hp_l + sa * 256);
        u16x4 vb = *(const u16x4*)(hp_l + sb * 256);
        u16x4 vc = *(const u16x4*)(hp_l + sc * 256);
        u16x4 vd = *(const u16x4*)(hp_l + sd * 256);
        dn0 += pA; dn1 += pB; dn2 += pC; dn3 += pD;
        ac0.x += pA * bf2f(va[0]); ac0.y += pA * bf2f(va[1]);
        ac0.z += pA * bf2f(va[2]); ac0.w += pA * bf2f(va[3]);
        ac1.x += pB * bf2f(vb[0]); ac1.y += pB * bf2f(vb[1]);
        ac1.z += pB * bf2f(vb[2]); ac1.w += pB * bf2f(vb[3]);
        ac2.x += pC * bf2f(vc[0]); ac2.y += pC * bf2f(vc[1]);
        ac2.z += pC * bf2f(vc[2]); ac2.w += pC * bf2f(vc[3]);
        ac3.x += pD * bf2f(vd[0]); ac3.y += pD * bf2f(vd[1]);
        ac3.z += pD * bf2f(vd[2]); ac3.w += pD * bf2f(vd[3]);
    }
    for (; j < s1; ++j) {
        int sa = srcs[j];
        float pA = pp[j * 4];
        u16x4 va = *(const u16x4*)(hp_l + sa * 256);
        dn0 += pA;
        ac0.x += pA * bf2f(va[0]); ac0.y += pA * bf2f(va[1]);
        ac0.z += pA * bf2f(va[2]); ac0.w += pA * bf2f(va[3]);
    }

    float4 acc = make_float4(ac0.x + ac1.x + ac2.x + ac3.x,
                             ac0.y + ac1.y + ac2.y + ac3.y,
                             ac0.z + ac1.z + ac2.z + ac3.z,
                             ac0.w + ac1.w + ac2.w + ac3.w);
    float r = 1.f / (dn0 + dn1 + dn2 + dn3 + 1e-16f);
    acc.x *= r; acc.y *= r; acc.z *= r; acc.w *= r;

    if (LAYER == 0) {
        u16* oh = oh_all + (size_t)side * n * 256;
        u16* ol = ol_all + (size_t)side * n * 256;
        float f[4] = { acc.x, acc.y, acc.z, acc.w };
        u16x4 hi, lo;
        #pragma unroll
        for (int c = 0; c < 4; ++c) {
            float e = (f[c] > 0.f) ? f[c] : expm1f(f[c]);
            u16 hh = f2bf(e);
            hi[c] = hh;
            lo[c] = f2bf(e - bf2f(hh));
        }
        *(u16x4*)(oh + (size_t)v * 256 + l * 4) = hi;
        *(u16x4*)(ol + (size_t)v * 256 + l * 4) = lo;
    } else {
        float* of = of_all + (size_t)side * n * 64;
        acc.x += __shfl_xor(acc.x, 16, 64); acc.y += __shfl_xor(acc.y, 16, 64);
        acc.z += __shfl_xor(acc.z, 16, 64); acc.w += __shfl_xor(acc.w, 16, 64);
        acc.x += __shfl_xor(acc.x, 32, 64); acc.y += __shfl_xor(acc.y, 32, 64);
        acc.z += __shfl_xor(acc.z, 32, 64); acc.w += __shfl_xor(acc.w, 32, 64);
        if (l < 16) {
            acc.x *= 0.25f; acc.y *= 0.25f; acc.z *= 0.25f; acc.w *= 0.25f;
            *(float4*)(of + (size_t)v * 64 + l * 4) = acc;
        }
    }
}

// ---------------------------------------------------------------------------
// final: logits = [out_u | out_t] @ fc_w + fc_b ; log_softmax over 16
// ---------------------------------------------------------------------------
__global__ __launch_bounds__(256) void final_k(
    const float* __restrict__ out_u, const float* __restrict__ out_t,
    const float* __restrict__ fcw, const float* __restrict__ fcb,
    float* __restrict__ out, int nret)
{
    int gid = blockIdx.x * blockDim.x + threadIdx.x;
    int nn = gid >> 4;
    int j  = gid & 15;
    if (nn >= nret) return;
    const float* ru = out_u + (size_t)nn * 64;
    const float* rt = out_t + (size_t)nn * 64;
    float acc = fcb[j];
    #pragma unroll 8
    for (int k = 0; k < 64; ++k) acc += ru[k] * fcw[k * 16 + j];
    #pragma unroll 8
    for (int k = 0; k < 64; ++k) acc += rt[k] * fcw[(64 + k) * 16 + j];

    float m = acc;
    for (int off = 8; off; off >>= 1) m = fmaxf(m, __shfl_xor(m, off, 16));
    float ex = expf(acc - m);
    float s = ex;
    for (int off = 8; off; off >>= 1) s += __shfl_xor(s, off, 16);
    out[(size_t)nn * 16 + j] = acc - m - logf(s);
}

// ---------------------------------------------------------------------------
extern "C" void kernel_launch(void* const* d_in, const int* in_sizes, int n_in,
                              void* d_out, int out_size, void* d_ws, size_t ws_size,
                              hipStream_t stream)
{
    const int N = in_sizes[0] / 256;     // 20000
    const int E = in_sizes[2];           // 320000
    const int NRET = out_size / 16;      // 20000

    const float* emb[2]  = { (const float*)d_in[0], (const float*)d_in[1] };
    const int*   srcI[2] = { (const int*)d_in[2], (const int*)d_in[4] };
    const int*   trgI[2] = { (const int*)d_in[3], (const int*)d_in[5] };
    const float* fcw = (const float*)d_in[18];
    const float* fcb = (const float*)d_in[19];

    // workspace carve
    char* p = (char*)d_ws;
    u16* hpb  = (u16*)p;    p += (size_t)2 * N * 256 * 2;
    u16* xh   = (u16*)p;    p += (size_t)2 * N * 256 * 2;
    u16* xl   = (u16*)p;    p += (size_t)2 * N * 256 * 2;
    u16* wht  = (u16*)p;    p += (size_t)4 * 65536 * 2;
    u16* wlt  = (u16*)p;    p += (size_t)4 * 65536 * 2;
    float* asat = (float*)p; p += (size_t)4 * N * 8 * 4;
    float* outs = (float*)p; p += (size_t)2 * N * 64 * 4;
    float* p4   = (float*)p; p += (size_t)2 * E * 4 * 4;
    int* starts2 = (int*)p; p += (size_t)2 * (N + 1) * 4;
    int* counts2 = (int*)p; p += (size_t)2 * N * 4;
    int* ranks2  = (int*)p; p += (size_t)2 * E * 4;
    int* srcs2   = (int*)p; p += (size_t)2 * E * 4;
    int* trgs2   = (int*)p; p += (size_t)2 * E * 4;

    const int E2B = (2 * E + 255) / 256;
    const dim3 gemm_grid((N + 63) / 64, 2);
    const dim3 split_grid((N * 64 + 255) / 256, 2);
    const dim3 agg_grid((N + 3) / 4, 2);
    const dim3 pexp_grid((E + 255) / 256, 2);

    hipMemsetAsync(counts2, 0, (size_t)2 * N * 4, stream);

    // CSR for both sides
    hist2_k<<<E2B, 256, 0, stream>>>(trgI[0], trgI[1], counts2, ranks2, E, N);
    scan2_k<<<2, 1024, 0, stream>>>(counts2, starts2, N);
    scatter2_k<<<E2B, 256, 0, stream>>>(srcI[0], srcI[1], trgI[0], trgI[1],
                                        starts2, ranks2, srcs2, trgs2, E, N);

    // all 4 weight splits (u0,u1,t0,t1)
    wsplit4_k<<<1024, 256, 0, stream>>>(
        (const float*)d_in[6], (const float*)d_in[9],
        (const float*)d_in[12], (const float*)d_in[15], wht, wlt);

    // both embeddings -> bf16 hi/lo
    splitx_k<<<split_grid, 256, 0, stream>>>(emb[0], emb[1], xh, xl, N * 64);

    for (int layer = 0; layer < 2; ++layer) {
        const float* au_s = (const float*)d_in[6 + 0 * 6 + layer * 3 + 1];
        const float* au_t = (const float*)d_in[6 + 0 * 6 + layer * 3 + 2];
        const float* at_s = (const float*)d_in[6 + 1 * 6 + layer * 3 + 1];
        const float* at_t = (const float*)d_in[6 + 1 * 6 + layer * 3 + 2];

        gemm_mfma_k<<<gemm_grid, 256, 0, stream>>>(
            xh, xl, wht, wlt, au_s, au_t, at_s, at_t, hpb, asat, layer, N);

        pexp_k<<<pexp_grid, 256, 0, stream>>>(srcs2, trgs2, asat, p4, layer, N, E);

        if (layer == 0)
            aggregate_k<0><<<agg_grid, 256, 0, stream>>>(
                hpb, p4, starts2, srcs2, xh, xl, nullptr, N, E);
        else
            aggregate_k<1><<<agg_grid, 256, 0, stream>>>(
                hpb, p4, starts2, srcs2, nullptr, nullptr, outs, N, E);
    }

    final_k<<<(NRET * 16 + 255) / 256, 256, 0, stream>>>(
        outs, outs + (size_t)N * 64, fcw, fcb, (float*)d_out, NRET);
}